// Round 6
// baseline (155.641 us; speedup 1.0000x reference)
//
#include <hip/hip_runtime.h>
#include <hip/hip_bf16.h>
#include <math.h>

#define Bg   128
#define Nn   64
#define Tt   256
#define INF  320      // Nn + Tt
#define Hd   256
#define OUTD 128
#define Ee   2016     // Nn*(Nn-1)/2
#define TOTE (Bg*Ee)  // 258048
#define SCOLS 576     // padded 514 -> 9*64 so GEMM2 tiles exactly
#define MROWS 8192    // Bg*Nn

#define RSQRT_LN2 1.2011224087864498f   // 1/sqrt(ln2): mean cols pre-scale
#define LOG2E     1.4426950408889634f
#define EPS_T     1.45719e-6f           // 1.01e-6 * log2e

typedef __attribute__((ext_vector_type(8))) short bf16x8;
typedef __attribute__((ext_vector_type(4))) float f32x4;

static __device__ __forceinline__ ushort f2bf(float v) {
    __hip_bfloat16 h = __float2bfloat16(v);
    return *(ushort*)&h;
}

// ---------------- prep: WgT->bf16, packed WcatT->bf16, ebias, red init ----------------
#define CVT_N (INF * Hd)                  // 81920
#define PACK_N (Hd * SCOLS)               // 147456
__global__ void k_prep(const float* __restrict__ Wg, const float* __restrict__ Wm,
                       const float* __restrict__ Wv, const float* __restrict__ Ww,
                       const float* __restrict__ bm, const float* __restrict__ bv,
                       const float* __restrict__ bw,
                       ushort* __restrict__ WgbT, ushort* __restrict__ WcatT,
                       float* __restrict__ ebias, unsigned* __restrict__ red) {
    int idx = blockIdx.x * 256 + threadIdx.x;
    if (idx == 0) { red[0] = 0u; red[1] = 0u; }
    if (idx < CVT_N) {
        int n = idx / INF, k = idx - n * INF;
        WgbT[idx] = f2bf(Wg[k * Hd + n]);
        return;
    }
    idx -= CVT_N;
    if (idx < PACK_N) {
        int n = idx / Hd, k = idx - n * Hd;   // n = output col, k = reduction
        float v = 0.f;
        if (n < 128)       v = Wm[k * 128 + n];
        else if (n < 256)  v = Wm[(256 + k) * 128 + (n - 128)];
        else if (n < 384)  v = Wv[k * 128 + (n - 256)];
        else if (n < 512)  v = Wv[(256 + k) * 128 + (n - 384)];
        else if (n == 512) v = Ww[k];
        else if (n == 513) v = Ww[256 + k];
        WcatT[idx] = f2bf(v);
        return;
    }
    idx -= PACK_N;
    if (idx >= SCOLS) return;
    float e = 0.f;
    if (idx < 128)                    e = bm[idx];
    else if (idx >= 256 && idx < 384) e = bv[idx - 256];
    else if (idx == 512)              e = bw[0];
    ebias[idx] = e;
}

// ---------------- prefix-mean aggregation: LDS-tiled coalesced scan ----------------
__global__ __launch_bounds__(256) void k_agg(const float* __restrict__ topo,
                                             const float* __restrict__ temp,
                                             ushort* __restrict__ agg) {
    __shared__ float T[64 * 65];
    const int b = blockIdx.x, ft = blockIdx.y;
    const int tid = threadIdx.x;
    const int row = tid >> 2, seg = tid & 3;
    const float* src = (ft == 0) ? (topo + (size_t)(b * Nn + row) * Nn)
                                 : (temp + (size_t)(b * Nn + row) * Tt + (ft - 1) * 64);
    #pragma unroll
    for (int i = 0; i < 4; ++i) {
        float4 v = *(const float4*)(src + seg * 16 + i * 4);
        float* d = &T[row * 65 + seg * 16 + i * 4];
        d[0] = v.x; d[1] = v.y; d[2] = v.z; d[3] = v.w;
    }
    __syncthreads();
    const int w = tid >> 6, lane = tid & 63;
    #pragma unroll
    for (int k = 0; k < 16; ++k) {
        int f = w * 16 + k;
        float x = T[lane * 65 + f];
        float incl = x;
        #pragma unroll
        for (int o = 1; o < 64; o <<= 1) {
            float t = __shfl_up(incl, o);
            if (lane >= o) incl += t;
        }
        float excl = incl - x;
        T[lane * 65 + f] = lane ? excl * __builtin_amdgcn_rcpf((float)lane) : 0.f;
    }
    __syncthreads();
    const int node = tid >> 2, f0 = (tid & 3) * 16;
    ushort tmp[16];
    #pragma unroll
    for (int i = 0; i < 16; ++i) tmp[i] = f2bf(T[node * 65 + f0 + i]);
    ushort* dst = agg + (size_t)(b * Nn + node) * INF + ft * 64 + f0;
    *(uint4*)dst = *(uint4*)tmp;
    *(uint4*)(dst + 8) = *(uint4*)(tmp + 8);
}

// ---------------- bf16 MFMA GEMM, 64x64 tile, BK=64, B pre-transposed ----------------
// edgeScale (transC only): cols 0-255 *= 1/sqrt(ln2); cols 256-511 -> exp(v)
// (stored as e^v so the edge kernel's softplus is log2(1+Ei*Ej): 2 transc/eterm).
__global__ __launch_bounds__(256) void k_gemm_mfma(const ushort* __restrict__ A,
                                                   const ushort* __restrict__ BT,
                                                   const float* __restrict__ bias,
                                                   ushort* __restrict__ Cb,
                                                   float* __restrict__ Cf,
                                                   int N, int K, int relu, int transC,
                                                   int edgeScale) {
    __shared__ ushort Asl[64 * 72];
    __shared__ ushort Bsl[64 * 72];   // [n][k]
    const int tid = threadIdx.x;
    const int w = tid >> 6, lane = tid & 63;
    const int quad = lane >> 4, r16 = lane & 15;
    const int m0 = blockIdx.y * 64, n0 = blockIdx.x * 64;
    const int row = tid >> 2, seg = tid & 3;
    f32x4 acc[4] = {};

    for (int k0 = 0; k0 < K; k0 += 64) {
        const ushort* ap = A + (size_t)(m0 + row) * K + k0 + seg * 16;
        uint4 a0 = ((const uint4*)ap)[0];
        uint4 a1 = ((const uint4*)ap)[1];
        *(uint4*)(Asl + row * 72 + seg * 16)     = a0;
        *(uint4*)(Asl + row * 72 + seg * 16 + 8) = a1;
        const ushort* bp = BT + (size_t)(n0 + row) * K + k0 + seg * 16;
        uint4 b0 = ((const uint4*)bp)[0];
        uint4 b1 = ((const uint4*)bp)[1];
        *(uint4*)(Bsl + row * 72 + seg * 16)     = b0;
        *(uint4*)(Bsl + row * 72 + seg * 16 + 8) = b1;
        __syncthreads();

        bf16x8 af0 = *(const bf16x8*)(Asl + (w * 16 + r16) * 72 + quad * 8);
        bf16x8 af1 = *(const bf16x8*)(Asl + (w * 16 + r16) * 72 + 32 + quad * 8);
        #pragma unroll
        for (int ns = 0; ns < 4; ++ns) {
            bf16x8 bf0 = *(const bf16x8*)(Bsl + (ns * 16 + r16) * 72 + quad * 8);
            bf16x8 bf1 = *(const bf16x8*)(Bsl + (ns * 16 + r16) * 72 + 32 + quad * 8);
            acc[ns] = __builtin_amdgcn_mfma_f32_16x16x32_bf16(af0, bf0, acc[ns], 0, 0, 0);
            acc[ns] = __builtin_amdgcn_mfma_f32_16x16x32_bf16(af1, bf1, acc[ns], 0, 0, 0);
        }
        __syncthreads();
    }

    const int row0 = m0 + w * 16 + quad * 4;
    #pragma unroll
    for (int ns = 0; ns < 4; ++ns) {
        f32x4 a = acc[ns];
        int col = n0 + ns * 16 + r16;
        float bb = bias ? bias[col] : 0.f;
        float vv[4];
        #pragma unroll
        for (int i = 0; i < 4; ++i) {
            float v = a[i] + bb;
            if (relu) v = fmaxf(v, 0.f);
            vv[i] = v;
        }
        if (transC) {
            if (edgeScale) {
                if (col < 256) {
                    #pragma unroll
                    for (int i = 0; i < 4; ++i) vv[i] *= RSQRT_LN2;
                } else if (col < 512) {
                    #pragma unroll
                    for (int i = 0; i < 4; ++i)
                        vv[i] = __builtin_amdgcn_exp2f(vv[i] * LOG2E);  // e^v
                }
            }
            *(float4*)(Cf + (size_t)col * MROWS + row0) = make_float4(vv[0], vv[1], vv[2], vv[3]);
        } else {
            #pragma unroll
            for (int i = 0; i < 4; ++i) {
                int row2 = row0 + i;
                if (Cb) Cb[(size_t)row2 * N + col] = f2bf(vv[i]);
                else    Cf[(size_t)row2 * N + col] = vv[i];
            }
        }
    }
}

// ---------------- edge kernel: 32-node group pairs, 2x2 pair blocking ----------------
// 1536 blocks = 128 graphs x 3 tiles {(0,0),(0,1),(1,1)} x 4 o-chunks of 32.
// 256 threads; each thread owns a 2x2 node cell -> 4 edges; per 4-o step it does
// 8 ds_read_b128 for 16 eterms (0.5 b128/eterm, half of round-1's ratio — the
// measured-insensitive-to-VALU/VGPR edge kernel is LDS-read-pipe bound at
// ~13us floor with 1 b128/eterm).
// LDS [4][32][36] f32 = 18.4KB, float4-granular XOR swizzle col^=((row>>1)&7)<<2
// (reads verified <=2-way conflict). Round-2 failure modes addressed:
// cap 128 VGPR + unroll 2 (~96 live regs, no spill); 1536 blocks -> ~4/CU resident.
static __device__ __forceinline__ float et(float mA, float mB, float eA, float eB) {
    float m = mA + mB;                       // mean, pre-scaled by 1/sqrt(ln2)
    float E = eA * eB;                       // e^{vi+vj}
    float t = __builtin_amdgcn_logf(1.f + E) + EPS_T;   // softplus * log2e
    return m * m * __builtin_amdgcn_rcpf(t);
}

static __device__ __forceinline__ float et4(float4 ma, float4 mb, float4 ea, float4 eb) {
    return et(ma.x, mb.x, ea.x, eb.x) + et(ma.y, mb.y, ea.y, eb.y)
         + et(ma.z, mb.z, ea.z, eb.z) + et(ma.w, mb.w, ea.w, eb.w);
}

__global__ __launch_bounds__(256, 4) void k_edge6(const float* __restrict__ ST,
                                                  float* __restrict__ accp) {
    __shared__ float L[4][32][36];
    const int bid = blockIdx.x;
    // XCD swizzle: 1536 = 8 XCDs x 192; 192 = 16 graphs x 12 (3 tiles x 4 oc)
    const int xcd = bid & 7, kk = bid >> 3;
    const int b = xcd * 16 + kk / 12;
    const int sub = kk - (kk / 12) * 12;
    const int tile = sub >> 2, oc = sub & 3;
    const int g0 = (tile == 2) ? 1 : 0;
    const int g1 = (tile == 0) ? 0 : 1;
    const int tid = threadIdx.x;

    // stage: arrays {mean-src g0, mean-dst g1, e^v-src g0, e^v-dst g1}
    // global o-row = arr*128 + oc*32 + c; transpose-scatter into [node][o^sw]
    {
        const int c = tid >> 3, n4 = (tid & 7) << 2;
        #pragma unroll
        for (int arr = 0; arr < 4; ++arr) {
            const int g = (arr & 1) ? g1 : g0;
            float4 v = *(const float4*)&ST[(size_t)(arr * 128 + oc * 32 + c) * MROWS
                                           + b * 64 + g * 32 + n4];
            #pragma unroll
            for (int di = 0; di < 4; ++di) {
                const int n = n4 + di;
                const int sw = ((n >> 1) & 7) << 2;
                L[arr][n][c ^ sw] = ((const float*)&v)[di];
            }
        }
    }

    // cell decode: full tile (g0!=g1): 16x16 cells on 256 threads.
    // diag tile: 120 strict cells (ci<cj) on tids 0..119 + 16 single-pair
    // diagonal cells on tids 120..135; rest idle.
    bool valid, diagcell = false;
    int i0, j0;
    if (g0 != g1) {
        valid = true;
        i0 = (tid >> 4) * 2; j0 = (tid & 15) * 2;
    } else if (tid < 120) {
        valid = true;
        int ii = 0, rr = tid;
        while (rr >= 15 - ii) { rr -= 15 - ii; ++ii; }
        i0 = ii * 2; j0 = (ii + 1 + rr) * 2;
    } else if (tid < 136) {
        valid = true; diagcell = true;
        int d = tid - 120;
        i0 = 2 * d; j0 = 2 * d + 1;       // single edge (2d, 2d+1)
    } else {
        valid = false; i0 = 0; j0 = 2;
    }
    const int i1 = diagcell ? i0 : i0 + 1;
    const int j1 = diagcell ? j0 : j0 + 1;
    const int swi0 = ((i0 >> 1) & 7) << 2, swi1 = ((i1 >> 1) & 7) << 2;
    const int swj0 = ((j0 >> 1) & 7) << 2, swj1 = ((j1 >> 1) & 7) << 2;

    __syncthreads();

    float a00 = 0.f, a01 = 0.f, a10 = 0.f, a11 = 0.f;
    if (valid) {
        #pragma unroll 2
        for (int t = 0; t < 32; t += 4) {
            float4 mi0 = *(const float4*)&L[0][i0][t ^ swi0];
            float4 mi1 = *(const float4*)&L[0][i1][t ^ swi1];
            float4 mj0 = *(const float4*)&L[1][j0][t ^ swj0];
            float4 mj1 = *(const float4*)&L[1][j1][t ^ swj1];
            float4 ei0 = *(const float4*)&L[2][i0][t ^ swi0];
            float4 ei1 = *(const float4*)&L[2][i1][t ^ swi1];
            float4 ej0 = *(const float4*)&L[3][j0][t ^ swj0];
            float4 ej1 = *(const float4*)&L[3][j1][t ^ swj1];
            a00 += et4(mi0, mj0, ei0, ej0);
            a01 += et4(mi0, mj1, ei0, ej1);
            a10 += et4(mi1, mj0, ei1, ej0);
            a11 += et4(mi1, mj1, ei1, ej1);
        }
    }

    if (valid) {
        const int ni0 = g0 * 32 + i0, ni1 = g0 * 32 + i1;
        const int nj0 = g1 * 32 + j0;
        float* ap = accp + (size_t)oc * TOTE + (size_t)b * Ee;
        if (diagcell) {
            ap[(ni0 * (127 - ni0)) / 2 + (nj0 - ni0 - 1)] = a00;
        } else {
            int e0 = (ni0 * (127 - ni0)) / 2 + (nj0 - ni0 - 1);
            int e1 = (ni1 * (127 - ni1)) / 2 + (nj0 - ni1 - 1);
            ap[e0] = a00; ap[e0 + 1] = a01;
            ap[e1] = a10; ap[e1 + 1] = a11;
        }
    }
}

// ---------------- gumbel/sigmoid numerator + softmax denominator ----------------
__global__ __launch_bounds__(256) void k_den(const float* __restrict__ ST,
                                             const float* __restrict__ gu,
                                             float* __restrict__ numer,
                                             unsigned* __restrict__ red) {
    __shared__ float sred[4];
    const int tid = threadIdx.x;
    int idx = blockIdx.x * 256 + tid;
    int b = idx >> 12, rem = idx & 4095;
    int r = rem >> 6, c = rem & 63;
    float en = 0.f;
    if (c > r) {
        int e = b * Ee + (r * (127 - r)) / 2 + (c - r - 1);
        float wr = ST[(size_t)512 * MROWS + b * 64 + r]
                 + ST[(size_t)513 * MROWS + b * 64 + c];
        float w  = __builtin_amdgcn_rcpf(1.f + __expf(-wr));
        float g  = -__logf(-__logf(gu[e]));
        en = __expf((w + g) * 2.0f);           // exp(logit/T), logit <= ~36: safe
        numer[e] = en;
    }
    float s = en;
    #pragma unroll
    for (int o = 32; o; o >>= 1) s += __shfl_down(s, o);
    if ((tid & 63) == 0) sred[tid >> 6] = s;
    __syncthreads();
    if (tid == 0) atomicAdd((float*)&red[1], sred[0] + sred[1] + sred[2] + sred[3]);
}

// ---------------- final scatter: combine acc partials, normalize, zero-fill ----------------
__global__ void k_out(const float* __restrict__ accp, const float* __restrict__ numer,
                      const unsigned* __restrict__ red, float* __restrict__ out) {
    int idx = blockIdx.x * 256 + threadIdx.x;
    if (idx >= Bg * Nn * Nn) return;
    int b = idx >> 12;
    int rem = idx & 4095;
    int r = rem >> 6, c = rem & 63;
    float v = 0.f;
    if (c > r) {
        int e = b * Ee + (r * (127 - r)) / 2 + (c - r - 1);
        float a = accp[e] + accp[TOTE + e] + accp[2 * TOTE + e] + accp[3 * TOTE + e];
        float se = __expf(a * (-1.f / 256.f));
        float Sinv = __builtin_amdgcn_rcpf(((const float*)red)[1]);
        v = se * numer[e] * Sinv;
    }
    out[idx] = v;
}

extern "C" void kernel_launch(void* const* d_in, const int* in_sizes, int n_in,
                              void* d_out, int out_size, void* d_ws, size_t ws_size,
                              hipStream_t stream) {
    const float* topo = (const float*)d_in[0];
    const float* temp = (const float*)d_in[1];
    const float* gu   = (const float*)d_in[2];
    const float* Wg   = (const float*)d_in[3];
    const float* bg   = (const float*)d_in[4];
    const float* Wm   = (const float*)d_in[5];
    const float* bm   = (const float*)d_in[6];
    const float* Wv   = (const float*)d_in[7];
    const float* bv   = (const float*)d_in[8];
    const float* Ww   = (const float*)d_in[9];
    const float* bw   = (const float*)d_in[10];
    float* out = (float*)d_out;

    char* ws = (char*)d_ws;
    size_t off = 0;
    auto carve = [&](size_t bytes) { char* p = ws + off; off = (off + bytes + 255) & ~(size_t)255; return p; };

    // r1 hosts aggb (bf16, 5.2 MB) pre-GEMM1, then S_T[576][8192] f32 (18.9 MB).
    char*   r1    = carve((size_t)SCOLS * MROWS * 4);
    float*  ST    = (float*)r1;
    ushort* aggb  = (ushort*)r1;
    ushort* hb    = (ushort*)carve((size_t)MROWS * Hd * 2);      // 4.19 MB
    ushort* WgbT  = (ushort*)carve((size_t)INF * Hd * 2);        // 0.16 MB
    ushort* WcatT = (ushort*)carve((size_t)Hd * SCOLS * 2);      // 0.29 MB
    float*  ebias = (float*)carve((size_t)SCOLS * 4);
    float*  numer = (float*)carve((size_t)TOTE * 4);             // 1.03 MB
    float*  accp  = (float*)carve((size_t)4 * TOTE * 4);         // 4.13 MB
    unsigned* red = (unsigned*)carve(256);

    k_prep<<<(CVT_N + PACK_N + SCOLS + 255) / 256, 256, 0, stream>>>(
        Wg, Wm, Wv, Ww, bm, bv, bw, WgbT, WcatT, ebias, red);
    k_agg<<<dim3(Bg, INF / 64), 256, 0, stream>>>(topo, temp, aggb);
    // GEMM1: hb[8192,256] = relu(aggb[8192,320] @ WgbT^T + bg)
    k_gemm_mfma<<<dim3(Hd / 64, MROWS / 64), 256, 0, stream>>>(
        aggb, WgbT, bg, hb, nullptr, Hd, INF, 1, 0, 0);
    // GEMM2: ST[576][8192] = colxf((hb[8192,256] @ WcatT^T + ebias))^T
    k_gemm_mfma<<<dim3(SCOLS / 64, MROWS / 64), 256, 0, stream>>>(
        hb, WcatT, ebias, nullptr, ST, SCOLS, Hd, 0, 1, 1);
    k_edge6<<<Bg * 12, 256, 0, stream>>>(ST, accp);
    k_den<<<(Bg * Nn * Nn) / 256, 256, 0, stream>>>(ST, gu, numer, red);
    k_out<<<(Bg * Nn * Nn + 255) / 256, 256, 0, stream>>>(accp, numer, red, out);
}

// Round 7
// 132.056 us; speedup vs baseline: 1.1786x; 1.1786x over previous
//
#include <hip/hip_runtime.h>
#include <hip/hip_bf16.h>
#include <math.h>

#define Bg   128
#define Nn   64
#define Tt   256
#define INF  320      // Nn + Tt
#define Hd   256
#define OUTD 128
#define Ee   2016     // Nn*(Nn-1)/2
#define TOTE (Bg*Ee)  // 258048
#define SCOLS 576     // padded 514 -> 9*64 so GEMM2 tiles exactly
#define MROWS 8192    // Bg*Nn

#define RSQRT_LN2 1.2011224087864498f   // 1/sqrt(ln2): mean cols pre-scale
#define LOG2E     1.4426950408889634f
#define EPS_T     1.45719e-6f           // 1.01e-6 * log2e

typedef __attribute__((ext_vector_type(8))) short bf16x8;
typedef __attribute__((ext_vector_type(4))) float f32x4;

static __device__ __forceinline__ ushort f2bf(float v) {
    __hip_bfloat16 h = __float2bfloat16(v);
    return *(ushort*)&h;
}

// ---------------- prep: WgT->bf16, packed WcatT->bf16, ebias, red init ----------------
#define CVT_N (INF * Hd)                  // 81920
#define PACK_N (Hd * SCOLS)               // 147456
__global__ void k_prep(const float* __restrict__ Wg, const float* __restrict__ Wm,
                       const float* __restrict__ Wv, const float* __restrict__ Ww,
                       const float* __restrict__ bm, const float* __restrict__ bv,
                       const float* __restrict__ bw,
                       ushort* __restrict__ WgbT, ushort* __restrict__ WcatT,
                       float* __restrict__ ebias, unsigned* __restrict__ red) {
    int idx = blockIdx.x * 256 + threadIdx.x;
    if (idx == 0) { red[0] = 0u; red[1] = 0u; }
    if (idx < CVT_N) {
        int n = idx / INF, k = idx - n * INF;
        WgbT[idx] = f2bf(Wg[k * Hd + n]);
        return;
    }
    idx -= CVT_N;
    if (idx < PACK_N) {
        int n = idx / Hd, k = idx - n * Hd;   // n = output col, k = reduction
        float v = 0.f;
        if (n < 128)       v = Wm[k * 128 + n];
        else if (n < 256)  v = Wm[(256 + k) * 128 + (n - 128)];
        else if (n < 384)  v = Wv[k * 128 + (n - 256)];
        else if (n < 512)  v = Wv[(256 + k) * 128 + (n - 384)];
        else if (n == 512) v = Ww[k];
        else if (n == 513) v = Ww[256 + k];
        WcatT[idx] = f2bf(v);
        return;
    }
    idx -= PACK_N;
    if (idx >= SCOLS) return;
    float e = 0.f;
    if (idx < 128)                    e = bm[idx];
    else if (idx >= 256 && idx < 384) e = bv[idx - 256];
    else if (idx == 512)              e = bw[0];
    ebias[idx] = e;
}

// ---------------- prefix-mean aggregation: LDS-tiled coalesced scan ----------------
__global__ __launch_bounds__(256) void k_agg(const float* __restrict__ topo,
                                             const float* __restrict__ temp,
                                             ushort* __restrict__ agg) {
    __shared__ float T[64 * 65];
    const int b = blockIdx.x, ft = blockIdx.y;
    const int tid = threadIdx.x;
    const int row = tid >> 2, seg = tid & 3;
    const float* src = (ft == 0) ? (topo + (size_t)(b * Nn + row) * Nn)
                                 : (temp + (size_t)(b * Nn + row) * Tt + (ft - 1) * 64);
    #pragma unroll
    for (int i = 0; i < 4; ++i) {
        float4 v = *(const float4*)(src + seg * 16 + i * 4);
        float* d = &T[row * 65 + seg * 16 + i * 4];
        d[0] = v.x; d[1] = v.y; d[2] = v.z; d[3] = v.w;
    }
    __syncthreads();
    const int w = tid >> 6, lane = tid & 63;
    #pragma unroll
    for (int k = 0; k < 16; ++k) {
        int f = w * 16 + k;
        float x = T[lane * 65 + f];
        float incl = x;
        #pragma unroll
        for (int o = 1; o < 64; o <<= 1) {
            float t = __shfl_up(incl, o);
            if (lane >= o) incl += t;
        }
        float excl = incl - x;
        T[lane * 65 + f] = lane ? excl * __builtin_amdgcn_rcpf((float)lane) : 0.f;
    }
    __syncthreads();
    const int node = tid >> 2, f0 = (tid & 3) * 16;
    ushort tmp[16];
    #pragma unroll
    for (int i = 0; i < 16; ++i) tmp[i] = f2bf(T[node * 65 + f0 + i]);
    ushort* dst = agg + (size_t)(b * Nn + node) * INF + ft * 64 + f0;
    *(uint4*)dst = *(uint4*)tmp;
    *(uint4*)(dst + 8) = *(uint4*)(tmp + 8);
}

// ---------------- bf16 MFMA GEMM, 64x64 tile, BK=64, B pre-transposed ----------------
// edgeScale (transC only): cols 0-255 *= 1/sqrt(ln2); cols 256-511 -> exp(v)
// (stored as e^v so the edge kernel's softplus is log2(1+Ei*Ej): 2 transc/eterm).
__global__ __launch_bounds__(256) void k_gemm_mfma(const ushort* __restrict__ A,
                                                   const ushort* __restrict__ BT,
                                                   const float* __restrict__ bias,
                                                   ushort* __restrict__ Cb,
                                                   float* __restrict__ Cf,
                                                   int N, int K, int relu, int transC,
                                                   int edgeScale) {
    __shared__ ushort Asl[64 * 72];
    __shared__ ushort Bsl[64 * 72];   // [n][k]
    const int tid = threadIdx.x;
    const int w = tid >> 6, lane = tid & 63;
    const int quad = lane >> 4, r16 = lane & 15;
    const int m0 = blockIdx.y * 64, n0 = blockIdx.x * 64;
    const int row = tid >> 2, seg = tid & 3;
    f32x4 acc[4] = {};

    for (int k0 = 0; k0 < K; k0 += 64) {
        const ushort* ap = A + (size_t)(m0 + row) * K + k0 + seg * 16;
        uint4 a0 = ((const uint4*)ap)[0];
        uint4 a1 = ((const uint4*)ap)[1];
        *(uint4*)(Asl + row * 72 + seg * 16)     = a0;
        *(uint4*)(Asl + row * 72 + seg * 16 + 8) = a1;
        const ushort* bp = BT + (size_t)(n0 + row) * K + k0 + seg * 16;
        uint4 b0 = ((const uint4*)bp)[0];
        uint4 b1 = ((const uint4*)bp)[1];
        *(uint4*)(Bsl + row * 72 + seg * 16)     = b0;
        *(uint4*)(Bsl + row * 72 + seg * 16 + 8) = b1;
        __syncthreads();

        bf16x8 af0 = *(const bf16x8*)(Asl + (w * 16 + r16) * 72 + quad * 8);
        bf16x8 af1 = *(const bf16x8*)(Asl + (w * 16 + r16) * 72 + 32 + quad * 8);
        #pragma unroll
        for (int ns = 0; ns < 4; ++ns) {
            bf16x8 bf0 = *(const bf16x8*)(Bsl + (ns * 16 + r16) * 72 + quad * 8);
            bf16x8 bf1 = *(const bf16x8*)(Bsl + (ns * 16 + r16) * 72 + 32 + quad * 8);
            acc[ns] = __builtin_amdgcn_mfma_f32_16x16x32_bf16(af0, bf0, acc[ns], 0, 0, 0);
            acc[ns] = __builtin_amdgcn_mfma_f32_16x16x32_bf16(af1, bf1, acc[ns], 0, 0, 0);
        }
        __syncthreads();
    }

    const int row0 = m0 + w * 16 + quad * 4;
    #pragma unroll
    for (int ns = 0; ns < 4; ++ns) {
        f32x4 a = acc[ns];
        int col = n0 + ns * 16 + r16;
        float bb = bias ? bias[col] : 0.f;
        float vv[4];
        #pragma unroll
        for (int i = 0; i < 4; ++i) {
            float v = a[i] + bb;
            if (relu) v = fmaxf(v, 0.f);
            vv[i] = v;
        }
        if (transC) {
            if (edgeScale) {
                if (col < 256) {
                    #pragma unroll
                    for (int i = 0; i < 4; ++i) vv[i] *= RSQRT_LN2;
                } else if (col < 512) {
                    #pragma unroll
                    for (int i = 0; i < 4; ++i)
                        vv[i] = __builtin_amdgcn_exp2f(vv[i] * LOG2E);  // e^v
                }
            }
            *(float4*)(Cf + (size_t)col * MROWS + row0) = make_float4(vv[0], vv[1], vv[2], vv[3]);
        } else {
            #pragma unroll
            for (int i = 0; i < 4; ++i) {
                int row2 = row0 + i;
                if (Cb) Cb[(size_t)row2 * N + col] = f2bf(vv[i]);
                else    Cf[(size_t)row2 * N + col] = vv[i];
            }
        }
    }
}

// ---------------- fused edge kernel -> numer + denominator atomic ----------------
// ROUND-5 STRUCTURE (grid 1280 = 128 graphs x 10 tiles, XCD-swizzled, LDS
// [4][16][68], 2 o-phases of 64, fused gumbel/sigmoid tail + block reduce).
// ROUND-7 COMPUTE REMAP (no structural change):
//  * lane -> 2x2 node cell (8x8 cells = 16x16 pairs per wave); wave -> 16-o slice
//    (4 waves x 16 o x 2 phases = 128 o). Per 4-o step: 8 ds_read_b128 feed 16
//    eterms (was 4 reads / 4 eterms) -> LDS instrs halved, 4x math per read.
//    Per-thread work unchanged (128 eterms). Diag tiles: 36/64 lanes active
//    (was 120/256). Per-edge accs summed across the 4 waves via a 4KB LDS pass
//    overlaid on L (+2 barriers, no extra dispatch).
//  * T14 async-stage: phase-1 global loads issue into 16 regs right after the
//    first barrier; the vmcnt(0) drain at the post-compute barrier lands after
//    ~1600 cy of phase-0 math -> staging latency hidden.
static __device__ __forceinline__ float et(float mA, float mB, float eA, float eB) {
    float m = mA + mB;                       // mean, pre-scaled by 1/sqrt(ln2)
    float E = eA * eB;                       // e^{vi+vj}
    float t = __builtin_amdgcn_logf(1.f + E) + EPS_T;   // softplus * log2e
    return m * m * __builtin_amdgcn_rcpf(t);
}

static __device__ __forceinline__ float et4(float4 ma, float4 mb, float4 ea, float4 eb) {
    return et(ma.x, mb.x, ea.x, eb.x) + et(ma.y, mb.y, ea.y, eb.y)
         + et(ma.z, mb.z, ea.z, eb.z) + et(ma.w, mb.w, ea.w, eb.w);
}

static __device__ __forceinline__ void cphase(const float (*L)[16][68], int w,
                                              int i0, int i1, int j0, int j1,
                                              float& a00, float& a01,
                                              float& a10, float& a11) {
    #pragma unroll 2
    for (int s = 0; s < 4; ++s) {
        const int t = (w << 4) + (s << 2);
        float4 mi0 = *(const float4*)&L[0][i0][t];
        float4 mi1 = *(const float4*)&L[0][i1][t];
        float4 mj0 = *(const float4*)&L[1][j0][t];
        float4 mj1 = *(const float4*)&L[1][j1][t];
        float4 ei0 = *(const float4*)&L[2][i0][t];
        float4 ei1 = *(const float4*)&L[2][i1][t];
        float4 ej0 = *(const float4*)&L[3][j0][t];
        float4 ej1 = *(const float4*)&L[3][j1][t];
        a00 += et4(mi0, mj0, ei0, ej0);
        a01 += et4(mi0, mj1, ei0, ej1);
        a10 += et4(mi1, mj0, ei1, ej0);
        a11 += et4(mi1, mj1, ei1, ej1);
    }
}

__global__ __launch_bounds__(256, 4) void k_edge4(const float* __restrict__ ST,
                                                  const float* __restrict__ gu,
                                                  float* __restrict__ numer,
                                                  unsigned* __restrict__ red) {
    __shared__ float L[4][16][68];      // 17408 B; reused as 1024-float acc buffer
    __shared__ float sred[4];
    float* R = &L[0][0][0];
    // XCD swizzle: bid%8 = XCD (round-robin dispatch); give each XCD 16 whole graphs.
    const int bid = blockIdx.x;
    const int xcd = bid & 7, kb = bid >> 3;         // kb in 0..159
    const int b = xcd * 16 + kb / 10;
    const int p = kb - (kb / 10) * 10;
    const int G0v[10] = {0,0,0,0,1,1,1,2,2,3};
    const int G1v[10] = {0,1,2,3,1,2,3,2,3,3};
    const int g0 = G0v[p], g1 = G1v[p];
    const int tid = threadIdx.x;
    const int w = tid >> 6, lane = tid & 63;

    // 2x2 cell decode: 8x8 cells cover the 16x16 pair tile
    const int ci = lane >> 3, cj = lane & 7;
    const int i0 = ci * 2, i1 = ci * 2 + 1;
    const int j0 = cj * 2, j1 = cj * 2 + 1;
    const bool cvalid = (g0 != g1) || (ci <= cj);   // lower-tri cells idle on diag tiles

    // staging coords (same scatter as round 5): c = o-row in phase, nq = node quad
    const int c = tid >> 2, nq = tid & 3;
    const size_t cbase = (size_t)b * 64;

    // ---- stage phase 0 ----
    #pragma unroll
    for (int arr = 0; arr < 4; ++arr) {
        const int g = (arr & 1) ? g1 : g0;
        float4 v = *(const float4*)&ST[(size_t)((arr << 7) + c) * MROWS
                                       + cbase + (g << 4) + (nq << 2)];
        L[arr][nq * 4 + 0][c] = v.x;
        L[arr][nq * 4 + 1][c] = v.y;
        L[arr][nq * 4 + 2][c] = v.z;
        L[arr][nq * 4 + 3][c] = v.w;
    }
    __syncthreads();

    // ---- T14: issue phase-1 loads now; drain lands after phase-0 compute ----
    float4 p1[4];
    #pragma unroll
    for (int arr = 0; arr < 4; ++arr) {
        const int g = (arr & 1) ? g1 : g0;
        p1[arr] = *(const float4*)&ST[(size_t)((arr << 7) + 64 + c) * MROWS
                                      + cbase + (g << 4) + (nq << 2)];
    }

    float a00 = 0.f, a01 = 0.f, a10 = 0.f, a11 = 0.f;
    if (cvalid) cphase(L, w, i0, i1, j0, j1, a00, a01, a10, a11);
    __syncthreads();                    // drains reads + p1 arrival (hidden)

    // ---- stage phase 1 from regs ----
    #pragma unroll
    for (int arr = 0; arr < 4; ++arr) {
        L[arr][nq * 4 + 0][c] = p1[arr].x;
        L[arr][nq * 4 + 1][c] = p1[arr].y;
        L[arr][nq * 4 + 2][c] = p1[arr].z;
        L[arr][nq * 4 + 3][c] = p1[arr].w;
    }
    __syncthreads();
    if (cvalid) cphase(L, w, i0, i1, j0, j1, a00, a01, a10, a11);
    __syncthreads();                    // all reads done before acc overlay

    // ---- cross-wave acc combine: wave w wrote o-slice partials ----
    *(float4*)&R[(w << 8) + (lane << 2)] = make_float4(a00, a01, a10, a11);
    __syncthreads();

    // thread t owns acc element t = cell*4 + k
    const int cell = tid >> 2, k = tid & 3;
    const int tci = cell >> 3, tcj = cell & 7;
    const int ti = 2 * tci + (k >> 1), tj = 2 * tcj + (k & 1);
    const int ni = g0 * 16 + ti, nj = g1 * 16 + tj;
    const bool tvalid = (g0 != g1) || (ti < tj);
    float en = 0.f;
    if (tvalid) {
        float a = R[tid] + R[256 + tid] + R[512 + tid] + R[768 + tid];
        int e = b * Ee + (ni * (127 - ni)) / 2 + (nj - ni - 1);
        float se = __expf(a * (-1.f / 256.f));   // a == sum m^2/(sp+1.01e-6) exactly
        float wr = ST[(size_t)512 * MROWS + cbase + ni]
                 + ST[(size_t)513 * MROWS + cbase + nj];   // w rows unscaled
        float wgt = __builtin_amdgcn_rcpf(1.f + __expf(-wr));
        float g   = -__logf(-__logf(gu[e]));
        en = __expf((wgt + g) * 2.0f);           // exp(logit), logit <= ~36: safe
        numer[e] = se * en;
    }
    // block reduce en for the softmax denominator: wave shuffle + 4-slot LDS
    float s = en;
    #pragma unroll
    for (int o = 32; o; o >>= 1) s += __shfl_down(s, o);
    if ((tid & 63) == 0) sred[tid >> 6] = s;
    __syncthreads();
    if (tid == 0) atomicAdd((float*)&red[1], sred[0] + sred[1] + sred[2] + sred[3]);
}

// ---------------- final scatter (also zero-fills) ----------------
__global__ void k_out(const float* __restrict__ numer, const unsigned* __restrict__ red,
                      float* __restrict__ out) {
    int idx = blockIdx.x * 256 + threadIdx.x;
    if (idx >= Bg * Nn * Nn) return;
    int b = idx >> 12;
    int rem = idx & 4095;
    int r = rem >> 6, c = rem & 63;
    float v = 0.f;
    if (c > r) {
        int e = b * Ee + (r * (127 - r)) / 2 + (c - r - 1);
        float Sinv = __builtin_amdgcn_rcpf(((const float*)red)[1]);
        v = numer[e] * Sinv;
    }
    out[idx] = v;
}

extern "C" void kernel_launch(void* const* d_in, const int* in_sizes, int n_in,
                              void* d_out, int out_size, void* d_ws, size_t ws_size,
                              hipStream_t stream) {
    const float* topo = (const float*)d_in[0];
    const float* temp = (const float*)d_in[1];
    const float* gu   = (const float*)d_in[2];
    const float* Wg   = (const float*)d_in[3];
    const float* bg   = (const float*)d_in[4];
    const float* Wm   = (const float*)d_in[5];
    const float* bm   = (const float*)d_in[6];
    const float* Wv   = (const float*)d_in[7];
    const float* bv   = (const float*)d_in[8];
    const float* Ww   = (const float*)d_in[9];
    const float* bw   = (const float*)d_in[10];
    float* out = (float*)d_out;

    char* ws = (char*)d_ws;
    size_t off = 0;
    auto carve = [&](size_t bytes) { char* p = ws + off; off = (off + bytes + 255) & ~(size_t)255; return p; };

    // r1 hosts aggb (bf16, 5.2 MB) pre-GEMM1, then S_T[576][8192] f32 (18.9 MB).
    char*   r1    = carve((size_t)SCOLS * MROWS * 4);
    float*  ST    = (float*)r1;
    ushort* aggb  = (ushort*)r1;
    ushort* hb    = (ushort*)carve((size_t)MROWS * Hd * 2);      // 4.19 MB
    ushort* WgbT  = (ushort*)carve((size_t)INF * Hd * 2);        // 0.16 MB
    ushort* WcatT = (ushort*)carve((size_t)Hd * SCOLS * 2);      // 0.29 MB
    float*  ebias = (float*)carve((size_t)SCOLS * 4);
    float*  numer = (float*)carve((size_t)TOTE * 4);             // 1.03 MB
    unsigned* red = (unsigned*)carve(256);

    k_prep<<<(CVT_N + PACK_N + SCOLS + 255) / 256, 256, 0, stream>>>(
        Wg, Wm, Wv, Ww, bm, bv, bw, WgbT, WcatT, ebias, red);
    k_agg<<<dim3(Bg, INF / 64), 256, 0, stream>>>(topo, temp, aggb);
    // GEMM1: hb[8192,256] = relu(aggb[8192,320] @ WgbT^T + bg)
    k_gemm_mfma<<<dim3(Hd / 64, MROWS / 64), 256, 0, stream>>>(
        aggb, WgbT, bg, hb, nullptr, Hd, INF, 1, 0, 0);
    // GEMM2: ST[576][8192] = colxf((hb[8192,256] @ WcatT^T + ebias))^T
    k_gemm_mfma<<<dim3(SCOLS / 64, MROWS / 64), 256, 0, stream>>>(
        hb, WcatT, ebias, nullptr, ST, SCOLS, Hd, 0, 1, 1);
    k_edge4<<<Bg * 10, 256, 0, stream>>>(ST, gu, numer, red);
    k_out<<<(Bg * Nn * Nn + 255) / 256, 256, 0, stream>>>(numer, red, out);
}

// Round 8
// 131.556 us; speedup vs baseline: 1.1831x; 1.0038x over previous
//
#include <hip/hip_runtime.h>
#include <hip/hip_bf16.h>
#include <math.h>

#define Bg   128
#define Nn   64
#define Tt   256
#define INF  320      // Nn + Tt
#define Hd   256
#define OUTD 128
#define Ee   2016     // Nn*(Nn-1)/2
#define TOTE (Bg*Ee)  // 258048
#define SCOLS 576     // padded 514 -> 9*64 so GEMM2 tiles exactly
#define MROWS 8192    // Bg*Nn

#define RSQRT_LN2 1.2011224087864498f   // 1/sqrt(ln2): mean cols pre-scale
#define LOG2E     1.4426950408889634f
#define EPS_T     1.45719e-6f           // 1.01e-6 * log2e

typedef __attribute__((ext_vector_type(8))) short bf16x8;
typedef __attribute__((ext_vector_type(4))) float f32x4;

static __device__ __forceinline__ ushort f2bf(float v) {
    __hip_bfloat16 h = __float2bfloat16(v);
    return *(ushort*)&h;
}

// ---------------- prep: WgT->bf16, packed WcatT->bf16, ebias, red init ----------------
#define CVT_N (INF * Hd)                  // 81920
#define PACK_N (Hd * SCOLS)               // 147456
__global__ void k_prep(const float* __restrict__ Wg, const float* __restrict__ Wm,
                       const float* __restrict__ Wv, const float* __restrict__ Ww,
                       const float* __restrict__ bm, const float* __restrict__ bv,
                       const float* __restrict__ bw,
                       ushort* __restrict__ WgbT, ushort* __restrict__ WcatT,
                       float* __restrict__ ebias, unsigned* __restrict__ red) {
    int idx = blockIdx.x * 256 + threadIdx.x;
    if (idx == 0) { red[0] = 0u; red[1] = 0u; }
    if (idx < CVT_N) {
        int n = idx / INF, k = idx - n * INF;
        WgbT[idx] = f2bf(Wg[k * Hd + n]);
        return;
    }
    idx -= CVT_N;
    if (idx < PACK_N) {
        int n = idx / Hd, k = idx - n * Hd;   // n = output col, k = reduction
        float v = 0.f;
        if (n < 128)       v = Wm[k * 128 + n];
        else if (n < 256)  v = Wm[(256 + k) * 128 + (n - 128)];
        else if (n < 384)  v = Wv[k * 128 + (n - 256)];
        else if (n < 512)  v = Wv[(256 + k) * 128 + (n - 384)];
        else if (n == 512) v = Ww[k];
        else if (n == 513) v = Ww[256 + k];
        WcatT[idx] = f2bf(v);
        return;
    }
    idx -= PACK_N;
    if (idx >= SCOLS) return;
    float e = 0.f;
    if (idx < 128)                    e = bm[idx];
    else if (idx >= 256 && idx < 384) e = bv[idx - 256];
    else if (idx == 512)              e = bw[0];
    ebias[idx] = e;
}

// ---------------- prefix-mean aggregation: LDS-tiled coalesced scan ----------------
__global__ __launch_bounds__(256) void k_agg(const float* __restrict__ topo,
                                             const float* __restrict__ temp,
                                             ushort* __restrict__ agg) {
    __shared__ float T[64 * 65];
    const int b = blockIdx.x, ft = blockIdx.y;
    const int tid = threadIdx.x;
    const int row = tid >> 2, seg = tid & 3;
    const float* src = (ft == 0) ? (topo + (size_t)(b * Nn + row) * Nn)
                                 : (temp + (size_t)(b * Nn + row) * Tt + (ft - 1) * 64);
    #pragma unroll
    for (int i = 0; i < 4; ++i) {
        float4 v = *(const float4*)(src + seg * 16 + i * 4);
        float* d = &T[row * 65 + seg * 16 + i * 4];
        d[0] = v.x; d[1] = v.y; d[2] = v.z; d[3] = v.w;
    }
    __syncthreads();
    const int w = tid >> 6, lane = tid & 63;
    #pragma unroll
    for (int k = 0; k < 16; ++k) {
        int f = w * 16 + k;
        float x = T[lane * 65 + f];
        float incl = x;
        #pragma unroll
        for (int o = 1; o < 64; o <<= 1) {
            float t = __shfl_up(incl, o);
            if (lane >= o) incl += t;
        }
        float excl = incl - x;
        T[lane * 65 + f] = lane ? excl * __builtin_amdgcn_rcpf((float)lane) : 0.f;
    }
    __syncthreads();
    const int node = tid >> 2, f0 = (tid & 3) * 16;
    ushort tmp[16];
    #pragma unroll
    for (int i = 0; i < 16; ++i) tmp[i] = f2bf(T[node * 65 + f0 + i]);
    ushort* dst = agg + (size_t)(b * Nn + node) * INF + ft * 64 + f0;
    *(uint4*)dst = *(uint4*)tmp;
    *(uint4*)(dst + 8) = *(uint4*)(tmp + 8);
}

// ---------------- bf16 MFMA GEMM, 64x64 tile, BK=64, B pre-transposed ----------------
// edgeScale (transC only): cols 0-255 *= 1/sqrt(ln2); cols 256-511 -> exp(v)
// (stored as e^v so the edge kernel's softplus is log2(1+Ei*Ej): 2 transc/eterm).
__global__ __launch_bounds__(256) void k_gemm_mfma(const ushort* __restrict__ A,
                                                   const ushort* __restrict__ BT,
                                                   const float* __restrict__ bias,
                                                   ushort* __restrict__ Cb,
                                                   float* __restrict__ Cf,
                                                   int N, int K, int relu, int transC,
                                                   int edgeScale) {
    __shared__ ushort Asl[64 * 72];
    __shared__ ushort Bsl[64 * 72];   // [n][k]
    const int tid = threadIdx.x;
    const int w = tid >> 6, lane = tid & 63;
    const int quad = lane >> 4, r16 = lane & 15;
    const int m0 = blockIdx.y * 64, n0 = blockIdx.x * 64;
    const int row = tid >> 2, seg = tid & 3;
    f32x4 acc[4] = {};

    for (int k0 = 0; k0 < K; k0 += 64) {
        const ushort* ap = A + (size_t)(m0 + row) * K + k0 + seg * 16;
        uint4 a0 = ((const uint4*)ap)[0];
        uint4 a1 = ((const uint4*)ap)[1];
        *(uint4*)(Asl + row * 72 + seg * 16)     = a0;
        *(uint4*)(Asl + row * 72 + seg * 16 + 8) = a1;
        const ushort* bp = BT + (size_t)(n0 + row) * K + k0 + seg * 16;
        uint4 b0 = ((const uint4*)bp)[0];
        uint4 b1 = ((const uint4*)bp)[1];
        *(uint4*)(Bsl + row * 72 + seg * 16)     = b0;
        *(uint4*)(Bsl + row * 72 + seg * 16 + 8) = b1;
        __syncthreads();

        bf16x8 af0 = *(const bf16x8*)(Asl + (w * 16 + r16) * 72 + quad * 8);
        bf16x8 af1 = *(const bf16x8*)(Asl + (w * 16 + r16) * 72 + 32 + quad * 8);
        #pragma unroll
        for (int ns = 0; ns < 4; ++ns) {
            bf16x8 bf0 = *(const bf16x8*)(Bsl + (ns * 16 + r16) * 72 + quad * 8);
            bf16x8 bf1 = *(const bf16x8*)(Bsl + (ns * 16 + r16) * 72 + 32 + quad * 8);
            acc[ns] = __builtin_amdgcn_mfma_f32_16x16x32_bf16(af0, bf0, acc[ns], 0, 0, 0);
            acc[ns] = __builtin_amdgcn_mfma_f32_16x16x32_bf16(af1, bf1, acc[ns], 0, 0, 0);
        }
        __syncthreads();
    }

    const int row0 = m0 + w * 16 + quad * 4;
    #pragma unroll
    for (int ns = 0; ns < 4; ++ns) {
        f32x4 a = acc[ns];
        int col = n0 + ns * 16 + r16;
        float bb = bias ? bias[col] : 0.f;
        float vv[4];
        #pragma unroll
        for (int i = 0; i < 4; ++i) {
            float v = a[i] + bb;
            if (relu) v = fmaxf(v, 0.f);
            vv[i] = v;
        }
        if (transC) {
            if (edgeScale) {
                if (col < 256) {
                    #pragma unroll
                    for (int i = 0; i < 4; ++i) vv[i] *= RSQRT_LN2;
                } else if (col < 512) {
                    #pragma unroll
                    for (int i = 0; i < 4; ++i)
                        vv[i] = __builtin_amdgcn_exp2f(vv[i] * LOG2E);  // e^v
                }
            }
            *(float4*)(Cf + (size_t)col * MROWS + row0) = make_float4(vv[0], vv[1], vv[2], vv[3]);
        } else {
            #pragma unroll
            for (int i = 0; i < 4; ++i) {
                int row2 = row0 + i;
                if (Cb) Cb[(size_t)row2 * N + col] = f2bf(vv[i]);
                else    Cf[(size_t)row2 * N + col] = vv[i];
            }
        }
    }
}

// ---------------- fused edge kernel -> numer + denominator atomic ----------------
// ROUND-7 STRUCTURE (measured best: 132.1 total): grid 1280 = 128 graphs x 10
// tiles, XCD-swizzled, LDS [4][16][68], 2 o-phases; lane -> 2x2 cell (8x8 cells
// per wave), wave -> 16-o slice; T14 phase-1 reg prefetch; cross-wave acc
// combine via LDS overlay; fused gumbel/sigmoid tail + block reduce.
// ROUND-8 FIX (scheduling tail): grid = exactly 5 blocks/CU, but cap-128 VGPR
// limited residency to 4 blocks/CU -> every CU ran 4 blocks then its 5th ALONE
// (duration ~2T vs ideal 1.25T) — invisible to per-pipe counters, consistent
// with all four prior nulls. __launch_bounds__(256,5) -> cap 102 VGPR -> 5
// resident -> single block-wave, no tail, 20 waves/CU TLP. cphase unroll 2 -> 1
// keeps live state ~75 regs (8 float4 operands + 16 p1 + accs/addrs): no spill.
static __device__ __forceinline__ float et(float mA, float mB, float eA, float eB) {
    float m = mA + mB;                       // mean, pre-scaled by 1/sqrt(ln2)
    float E = eA * eB;                       // e^{vi+vj}
    float t = __builtin_amdgcn_logf(1.f + E) + EPS_T;   // softplus * log2e
    return m * m * __builtin_amdgcn_rcpf(t);
}

static __device__ __forceinline__ float et4(float4 ma, float4 mb, float4 ea, float4 eb) {
    return et(ma.x, mb.x, ea.x, eb.x) + et(ma.y, mb.y, ea.y, eb.y)
         + et(ma.z, mb.z, ea.z, eb.z) + et(ma.w, mb.w, ea.w, eb.w);
}

static __device__ __forceinline__ void cphase(const float (*L)[16][68], int w,
                                              int i0, int i1, int j0, int j1,
                                              float& a00, float& a01,
                                              float& a10, float& a11) {
    #pragma unroll 1
    for (int s = 0; s < 4; ++s) {
        const int t = (w << 4) + (s << 2);
        float4 mi0 = *(const float4*)&L[0][i0][t];
        float4 mi1 = *(const float4*)&L[0][i1][t];
        float4 mj0 = *(const float4*)&L[1][j0][t];
        float4 mj1 = *(const float4*)&L[1][j1][t];
        float4 ei0 = *(const float4*)&L[2][i0][t];
        float4 ei1 = *(const float4*)&L[2][i1][t];
        float4 ej0 = *(const float4*)&L[3][j0][t];
        float4 ej1 = *(const float4*)&L[3][j1][t];
        a00 += et4(mi0, mj0, ei0, ej0);
        a01 += et4(mi0, mj1, ei0, ej1);
        a10 += et4(mi1, mj0, ei1, ej0);
        a11 += et4(mi1, mj1, ei1, ej1);
    }
}

__global__ __launch_bounds__(256, 5) void k_edge4(const float* __restrict__ ST,
                                                  const float* __restrict__ gu,
                                                  float* __restrict__ numer,
                                                  unsigned* __restrict__ red) {
    __shared__ float L[4][16][68];      // 17408 B; reused as 1024-float acc buffer
    __shared__ float sred[4];
    float* R = &L[0][0][0];
    // XCD swizzle: bid%8 = XCD (round-robin dispatch); give each XCD 16 whole graphs.
    const int bid = blockIdx.x;
    const int xcd = bid & 7, kb = bid >> 3;         // kb in 0..159
    const int b = xcd * 16 + kb / 10;
    const int p = kb - (kb / 10) * 10;
    const int G0v[10] = {0,0,0,0,1,1,1,2,2,3};
    const int G1v[10] = {0,1,2,3,1,2,3,2,3,3};
    const int g0 = G0v[p], g1 = G1v[p];
    const int tid = threadIdx.x;
    const int w = tid >> 6, lane = tid & 63;

    // 2x2 cell decode: 8x8 cells cover the 16x16 pair tile
    const int ci = lane >> 3, cj = lane & 7;
    const int i0 = ci * 2, i1 = ci * 2 + 1;
    const int j0 = cj * 2, j1 = cj * 2 + 1;
    const bool cvalid = (g0 != g1) || (ci <= cj);   // lower-tri cells idle on diag tiles

    // staging coords (same scatter as round 5): c = o-row in phase, nq = node quad
    const int c = tid >> 2, nq = tid & 3;
    const size_t cbase = (size_t)b * 64;

    // ---- stage phase 0 ----
    #pragma unroll
    for (int arr = 0; arr < 4; ++arr) {
        const int g = (arr & 1) ? g1 : g0;
        float4 v = *(const float4*)&ST[(size_t)((arr << 7) + c) * MROWS
                                       + cbase + (g << 4) + (nq << 2)];
        L[arr][nq * 4 + 0][c] = v.x;
        L[arr][nq * 4 + 1][c] = v.y;
        L[arr][nq * 4 + 2][c] = v.z;
        L[arr][nq * 4 + 3][c] = v.w;
    }
    __syncthreads();

    // ---- T14: issue phase-1 loads now; drain lands after phase-0 compute ----
    float4 p1[4];
    #pragma unroll
    for (int arr = 0; arr < 4; ++arr) {
        const int g = (arr & 1) ? g1 : g0;
        p1[arr] = *(const float4*)&ST[(size_t)((arr << 7) + 64 + c) * MROWS
                                      + cbase + (g << 4) + (nq << 2)];
    }

    float a00 = 0.f, a01 = 0.f, a10 = 0.f, a11 = 0.f;
    if (cvalid) cphase(L, w, i0, i1, j0, j1, a00, a01, a10, a11);
    __syncthreads();                    // drains reads + p1 arrival (hidden)

    // ---- stage phase 1 from regs ----
    #pragma unroll
    for (int arr = 0; arr < 4; ++arr) {
        L[arr][nq * 4 + 0][c] = p1[arr].x;
        L[arr][nq * 4 + 1][c] = p1[arr].y;
        L[arr][nq * 4 + 2][c] = p1[arr].z;
        L[arr][nq * 4 + 3][c] = p1[arr].w;
    }
    __syncthreads();
    if (cvalid) cphase(L, w, i0, i1, j0, j1, a00, a01, a10, a11);
    __syncthreads();                    // all reads done before acc overlay

    // ---- cross-wave acc combine: wave w wrote o-slice partials ----
    *(float4*)&R[(w << 8) + (lane << 2)] = make_float4(a00, a01, a10, a11);
    __syncthreads();

    // thread t owns acc element t = cell*4 + k
    const int cell = tid >> 2, k = tid & 3;
    const int tci = cell >> 3, tcj = cell & 7;
    const int ti = 2 * tci + (k >> 1), tj = 2 * tcj + (k & 1);
    const int ni = g0 * 16 + ti, nj = g1 * 16 + tj;
    const bool tvalid = (g0 != g1) || (ti < tj);
    float en = 0.f;
    if (tvalid) {
        float a = R[tid] + R[256 + tid] + R[512 + tid] + R[768 + tid];
        int e = b * Ee + (ni * (127 - ni)) / 2 + (nj - ni - 1);
        float se = __expf(a * (-1.f / 256.f));   // a == sum m^2/(sp+1.01e-6) exactly
        float wr = ST[(size_t)512 * MROWS + cbase + ni]
                 + ST[(size_t)513 * MROWS + cbase + nj];   // w rows unscaled
        float wgt = __builtin_amdgcn_rcpf(1.f + __expf(-wr));
        float g   = -__logf(-__logf(gu[e]));
        en = __expf((wgt + g) * 2.0f);           // exp(logit), logit <= ~36: safe
        numer[e] = se * en;
    }
    // block reduce en for the softmax denominator: wave shuffle + 4-slot LDS
    float s = en;
    #pragma unroll
    for (int o = 32; o; o >>= 1) s += __shfl_down(s, o);
    if ((tid & 63) == 0) sred[tid >> 6] = s;
    __syncthreads();
    if (tid == 0) atomicAdd((float*)&red[1], sred[0] + sred[1] + sred[2] + sred[3]);
}

// ---------------- final scatter (also zero-fills) ----------------
__global__ void k_out(const float* __restrict__ numer, const unsigned* __restrict__ red,
                      float* __restrict__ out) {
    int idx = blockIdx.x * 256 + threadIdx.x;
    if (idx >= Bg * Nn * Nn) return;
    int b = idx >> 12;
    int rem = idx & 4095;
    int r = rem >> 6, c = rem & 63;
    float v = 0.f;
    if (c > r) {
        int e = b * Ee + (r * (127 - r)) / 2 + (c - r - 1);
        float Sinv = __builtin_amdgcn_rcpf(((const float*)red)[1]);
        v = numer[e] * Sinv;
    }
    out[idx] = v;
}

extern "C" void kernel_launch(void* const* d_in, const int* in_sizes, int n_in,
                              void* d_out, int out_size, void* d_ws, size_t ws_size,
                              hipStream_t stream) {
    const float* topo = (const float*)d_in[0];
    const float* temp = (const float*)d_in[1];
    const float* gu   = (const float*)d_in[2];
    const float* Wg   = (const float*)d_in[3];
    const float* bg   = (const float*)d_in[4];
    const float* Wm   = (const float*)d_in[5];
    const float* bm   = (const float*)d_in[6];
    const float* Wv   = (const float*)d_in[7];
    const float* bv   = (const float*)d_in[8];
    const float* Ww   = (const float*)d_in[9];
    const float* bw   = (const float*)d_in[10];
    float* out = (float*)d_out;

    char* ws = (char*)d_ws;
    size_t off = 0;
    auto carve = [&](size_t bytes) { char* p = ws + off; off = (off + bytes + 255) & ~(size_t)255; return p; };

    // r1 hosts aggb (bf16, 5.2 MB) pre-GEMM1, then S_T[576][8192] f32 (18.9 MB).
    char*   r1    = carve((size_t)SCOLS * MROWS * 4);
    float*  ST    = (float*)r1;
    ushort* aggb  = (ushort*)r1;
    ushort* hb    = (ushort*)carve((size_t)MROWS * Hd * 2);      // 4.19 MB
    ushort* WgbT  = (ushort*)carve((size_t)INF * Hd * 2);        // 0.16 MB
    ushort* WcatT = (ushort*)carve((size_t)Hd * SCOLS * 2);      // 0.29 MB
    float*  ebias = (float*)carve((size_t)SCOLS * 4);
    float*  numer = (float*)carve((size_t)TOTE * 4);             // 1.03 MB
    unsigned* red = (unsigned*)carve(256);

    k_prep<<<(CVT_N + PACK_N + SCOLS + 255) / 256, 256, 0, stream>>>(
        Wg, Wm, Wv, Ww, bm, bv, bw, WgbT, WcatT, ebias, red);
    k_agg<<<dim3(Bg, INF / 64), 256, 0, stream>>>(topo, temp, aggb);
    // GEMM1: hb[8192,256] = relu(aggb[8192,320] @ WgbT^T + bg)
    k_gemm_mfma<<<dim3(Hd / 64, MROWS / 64), 256, 0, stream>>>(
        aggb, WgbT, bg, hb, nullptr, Hd, INF, 1, 0, 0);
    // GEMM2: ST[576][8192] = colxf((hb[8192,256] @ WcatT^T + ebias))^T
    k_gemm_mfma<<<dim3(SCOLS / 64, MROWS / 64), 256, 0, stream>>>(
        hb, WcatT, ebias, nullptr, ST, SCOLS, Hd, 0, 1, 1);
    k_edge4<<<Bg * 10, 256, 0, stream>>>(ST, gu, numer, red);
    k_out<<<(Bg * Nn * Nn + 255) / 256, 256, 0, stream>>>(numer, red, out);
}